// Round 1
// baseline (1916.260 us; speedup 1.0000x reference)
//
#include <hip/hip_runtime.h>

#ifndef __has_builtin
#define __has_builtin(x) 0
#endif

// v_exp_f32 is 2^x, v_log_f32 is log2(x) on gfx950 — use raw builtins to avoid
// OCML wrapper overhead in the hot loop; guarded fallbacks keep it compiling.
__device__ __forceinline__ float fexp2(float x) {
#if __has_builtin(__builtin_amdgcn_exp2f)
    return __builtin_amdgcn_exp2f(x);
#else
    return exp2f(x);
#endif
}
__device__ __forceinline__ float flog2(float x) {
#if __has_builtin(__builtin_amdgcn_logf)
    return __builtin_amdgcn_logf(x);
#else
    return log2f(x);
#endif
}

// Problem constants (from reference): N=8192 nodes, S=64 samples, K=64 codes, d=128
// eps = 0.3, 50 Sinkhorn iterations, uniform marginals a=b=1/64.
// Work in base-2 scaled potentials: fh = f/(eps*ln2), gh = g/(eps*ln2),
// M2[i][j] = -C_ij/(eps*ln2) + log2(1/64)   (log2 b folded in; log a = log b here)
// Updates: fh_i = -LSE2_j(gh_j + M2_ij); gh_j = -LSE2_i(fh_i + M2_ij)
// hist_k  proportional to  sum_i 2^(fh_i + gh_k + M2_ik);  normalize at the end.

#define SS   64
#define KK   64
#define DD   128
#define MST  66              // LDS row stride: 66 -> banks (2i+j)%32, 2-way = free
#define NEG_INV_EPS_LN2  (-4.80898346962988f)   // -1/(0.3*ln2)

__global__ __launch_bounds__(64)
void node_sinkhorn_kernel(const float* __restrict__ samples,
                          const float* __restrict__ codebook,
                          float* __restrict__ out)
{
    __shared__ __align__(16) float M2[SS * MST];   // 16896 B
    __shared__ __align__(16) float fhs[SS];
    __shared__ __align__(16) float ghs[KK];
    __shared__ __align__(16) float syl[KK];

    const int node = blockIdx.x;
    const int lane = threadIdx.x;            // lane == sample row i == code col j

    // ---- codebook squared norms: lane k computes ||y_k||^2 ----
    {
        const float* cb = codebook + lane * DD;
        float a0 = 0.f, a1 = 0.f, a2 = 0.f, a3 = 0.f;
#pragma unroll
        for (int d = 0; d < DD; d += 4) {
            float4 v = *(const float4*)(cb + d);
            a0 = fmaf(v.x, v.x, a0); a1 = fmaf(v.y, v.y, a1);
            a2 = fmaf(v.z, v.z, a2); a3 = fmaf(v.w, v.w, a3);
        }
        syl[lane] = (a0 + a1) + (a2 + a3);
    }

    // ---- load this lane's sample row (128 floats in VGPRs) ----
    float4 xr[DD / 4];
    {
        const float* xp = samples + ((long)node * SS + lane) * DD;
#pragma unroll
        for (int c = 0; c < DD / 4; ++c) xr[c] = *(const float4*)(xp + 4 * c);
    }
    float sx;
    {
        float a0 = 0.f, a1 = 0.f, a2 = 0.f, a3 = 0.f;
#pragma unroll
        for (int c = 0; c < DD / 4; ++c) {
            a0 = fmaf(xr[c].x, xr[c].x, a0); a1 = fmaf(xr[c].y, xr[c].y, a1);
            a2 = fmaf(xr[c].z, xr[c].z, a2); a3 = fmaf(xr[c].w, xr[c].w, a3);
        }
        sx = (a0 + a1) + (a2 + a3);
    }
    __syncthreads();   // syl ready

    // ---- cost row: lane i computes M2[i][k] for all k (y reads are wave-uniform
    //      -> scalar loads; x stays in VGPRs) ----
#pragma unroll 1
    for (int k = 0; k < KK; ++k) {
        const float* yk = codebook + k * DD;
        float a0 = 0.f, a1 = 0.f, a2 = 0.f, a3 = 0.f;
#pragma unroll
        for (int c = 0; c < DD / 4; ++c) {
            a0 = fmaf(xr[c].x, yk[4 * c + 0], a0);
            a1 = fmaf(xr[c].y, yk[4 * c + 1], a1);
            a2 = fmaf(xr[c].z, yk[4 * c + 2], a2);
            a3 = fmaf(xr[c].w, yk[4 * c + 3], a3);
        }
        float dot = (a0 + a1) + (a2 + a3);
        float c2  = fmaf(-2.f, dot, sx + syl[k]);   // ||x||^2+||y||^2-2xy
        c2 = fmaxf(c2, 0.f);
        M2[lane * MST + k] = fmaf(c2, NEG_INV_EPS_LN2, -6.0f);  // + log2(1/64)
    }
    __syncthreads();

    const int rb = lane * MST;
    float fh, gh;

    // ---- iteration 1: full max-subtracted LSE (exponents ~ -1250) ----
    {
        float m = -3.4e38f;
#pragma unroll
        for (int j = 0; j < KK; j += 2) {
            float2 v = *(const float2*)&M2[rb + j];
            m = fmaxf(m, fmaxf(v.x, v.y));
        }
        float s0 = 0.f, s1 = 0.f;
#pragma unroll
        for (int j = 0; j < KK; j += 2) {
            float2 v = *(const float2*)&M2[rb + j];
            s0 += fexp2(v.x - m);
            s1 += fexp2(v.y - m);
        }
        fh = -(m + flog2(s0 + s1));
        fhs[lane] = fh;
    }
    __syncthreads();
    {
        float m = -3.4e38f;
#pragma unroll
        for (int i = 0; i < SS; ++i)
            m = fmaxf(m, fhs[i] + M2[i * MST + lane]);
        float s0 = 0.f, s1 = 0.f;
#pragma unroll
        for (int i = 0; i < SS; i += 2) {
            s0 += fexp2(fhs[i]     + M2[(i)     * MST + lane] - m);
            s1 += fexp2(fhs[i + 1] + M2[(i + 1) * MST + lane] - m);
        }
        gh = -(m + flog2(s0 + s1));
        ghs[lane] = gh;
    }
    __syncthreads();

    // ---- iterations 2..50: shifted form, exponents = log2(P_ij) <= 0,
    //      sums in [2^-6, 64] -> no max pass, no under/overflow ----
#pragma unroll 1
    for (int it = 0; it < 49; ++it) {
        // f-update (lane = row i): fh -= log2( sum_j 2^(gh_j + M2_ij + fh) )
        float s0 = 0.f, s1 = 0.f, s2 = 0.f, s3 = 0.f;
#pragma unroll
        for (int j = 0; j < KK; j += 4) {
            float2 g01 = *(const float2*)&ghs[j];
            float2 g23 = *(const float2*)&ghs[j + 2];
            float2 m01 = *(const float2*)&M2[rb + j];
            float2 m23 = *(const float2*)&M2[rb + j + 2];
            s0 += fexp2(g01.x + m01.x + fh);
            s1 += fexp2(g01.y + m01.y + fh);
            s2 += fexp2(g23.x + m23.x + fh);
            s3 += fexp2(g23.y + m23.y + fh);
        }
        fh -= flog2((s0 + s1) + (s2 + s3));
        fhs[lane] = fh;
        __syncthreads();

        // g-update (lane = col j): gh -= log2( sum_i 2^(fh_i + M2_ij + gh) )
        float t0 = 0.f, t1 = 0.f, t2 = 0.f, t3 = 0.f;
#pragma unroll
        for (int i = 0; i < SS; i += 4) {
            float2 f01 = *(const float2*)&fhs[i];
            float2 f23 = *(const float2*)&fhs[i + 2];
            t0 += fexp2(f01.x + M2[(i)     * MST + lane] + gh);
            t1 += fexp2(f01.y + M2[(i + 1) * MST + lane] + gh);
            t2 += fexp2(f23.x + M2[(i + 2) * MST + lane] + gh);
            t3 += fexp2(f23.y + M2[(i + 3) * MST + lane] + gh);
        }
        gh -= flog2((t0 + t1) + (t2 + t3));
        ghs[lane] = gh;
        __syncthreads();
    }

    // ---- epilogue: hist_k = sum_i 2^(fh_i + gh_k + M2_ik), normalized ----
    float h0 = 0.f, h1 = 0.f;
#pragma unroll
    for (int i = 0; i < SS; i += 2) {
        float2 f01 = *(const float2*)&fhs[i];
        h0 += fexp2(f01.x + M2[(i)     * MST + lane] + gh);
        h1 += fexp2(f01.y + M2[(i + 1) * MST + lane] + gh);
    }
    float h = h0 + h1;
    float tot = h;
#pragma unroll
    for (int off = 32; off > 0; off >>= 1) tot += __shfl_xor(tot, off);
    out[(long)node * KK + lane] = h / (tot + 6.4e-11f);
}

extern "C" void kernel_launch(void* const* d_in, const int* in_sizes, int n_in,
                              void* d_out, int out_size, void* d_ws, size_t ws_size,
                              hipStream_t stream) {
    const float* samples  = (const float*)d_in[0];
    const float* codebook = (const float*)d_in[1];
    float* out = (float*)d_out;
    const int N = in_sizes[0] / (SS * DD);   // 8192 nodes
    hipLaunchKernelGGL(node_sinkhorn_kernel, dim3(N), dim3(64), 0, stream,
                       samples, codebook, out);
}

// Round 2
// 289.369 us; speedup vs baseline: 6.6222x; 6.6222x over previous
//
#include <hip/hip_runtime.h>

// NodeSinkhornPooling — exact algebraic simplification.
//
// The reference runs 50 log-domain Sinkhorn iterations per node, but each
// iteration ENDS with a g-update, and a g-update enforces the column marginal
// exactly:  v_j = 1 / sum_i a_i u_i K_ij. The returned histogram is
//   hist_k = sum_i P_ik = b_k * v_k * sum_i a_i u_i K_ik = b_k
// identically — for any inputs, any iteration count. After normalization
// (sum_k b_k = 1) the output is the constant b_k = 1/64.
//
// Verified empirically: round-0 stub absmax vs reference was exactly
// 1/64 = 1.5625e-2 (reference is uniform); round-1 full solver matched the
// reference with absmax 0.0. Remaining deviation of the np/jax reference from
// exact 1/64 is its own fp32 round-off (~1e-7), 3 orders of magnitude below
// the 3.125e-4 threshold.
//
// Roofline: the computation reduces to storing out_size (8192*64) floats =
// 2 MiB -> ~0.33 us at 6.3 TB/s; wall time is launch-overhead bound.

#define KK 64

__global__ __launch_bounds__(256)
void node_sinkhorn_const_kernel(float4* __restrict__ out, int n4)
{
    const float b = 1.0f / (float)KK;            // 0.015625f, exact in fp32
    const float4 v = make_float4(b, b, b, b);
    int idx = blockIdx.x * 256 + threadIdx.x;
    int stride = gridDim.x * 256;
    for (int i = idx; i < n4; i += stride)
        out[i] = v;
}

extern "C" void kernel_launch(void* const* d_in, const int* in_sizes, int n_in,
                              void* d_out, int out_size, void* d_ws, size_t ws_size,
                              hipStream_t stream) {
    (void)d_in; (void)in_sizes; (void)n_in; (void)d_ws; (void)ws_size;
    // out_size = N*K floats (K=64); it is divisible by 4 (K=64).
    int n4 = out_size / 4;
    int blocks = (n4 + 255) / 256;
    if (blocks > 1024) blocks = 1024;            // grid-stride beyond this
    hipLaunchKernelGGL(node_sinkhorn_const_kernel, dim3(blocks), dim3(256), 0,
                       stream, (float4*)d_out, n4);
}